// Round 3
// baseline (1617.177 us; speedup 1.0000x reference)
//
#include <hip/hip_runtime.h>
#include <math.h>

#define B_   64
#define C_   768
#define HW_  1024          // 32*32
#define NCLS 100
#define E_   16
#define K_   2
#define FAN  (C_ + NCLS)   // 868
#define BLOCKS_PER_BATCH 192             // 768 rows / 4 rows per block
#define NBLK (B_ * BLOCKS_PER_BATCH)     // 12288

typedef float vfloat4 __attribute__((ext_vector_type(4)));

// One kernel: pool (one wave per (b,c) row) + last-block-per-batch runs the router.
__global__ __launch_bounds__(256) void fused_router(const float* __restrict__ x,
                                                    const float* __restrict__ task_cls,
                                                    const float* __restrict__ Wm,
                                                    const float* __restrict__ bias,
                                                    float* __restrict__ out,
                                                    float* __restrict__ pooled,
                                                    unsigned int* __restrict__ counters) {
    const int tid  = threadIdx.x;
    const int lane = tid & 63;
    const int wav  = tid >> 6;
    const int blk  = blockIdx.x;
    const int row  = blk * 4 + wav;          // b*768 + c
    const int b    = blk / BLOCKS_PER_BATCH; // batch this block serves

    // ---------- pool: mean over 1024 contiguous floats, one wave per row ----------
    const vfloat4* p = reinterpret_cast<const vfloat4*>(x + (size_t)row * HW_);
    vfloat4 va = __builtin_nontemporal_load(p + lane);
    vfloat4 vb = __builtin_nontemporal_load(p + lane + 64);
    vfloat4 vc = __builtin_nontemporal_load(p + lane + 128);
    vfloat4 vd = __builtin_nontemporal_load(p + lane + 192);
    float s = (va.x + va.y + va.z + va.w) + (vb.x + vb.y + vb.z + vb.w)
            + (vc.x + vc.y + vc.z + vc.w) + (vd.x + vd.y + vd.z + vd.w);
    #pragma unroll
    for (int off = 32; off > 0; off >>= 1) s += __shfl_down(s, off);
    if (lane == 0) pooled[row] = s * (1.0f / 1024.0f);

    // ---------- completion signal (release) ----------
    __threadfence();                         // make pooled[] stores device-visible
    __syncthreads();
    __shared__ unsigned int prev;
    if (tid == 0) prev = atomicAdd(&counters[b], 1u);
    __syncthreads();
    if (prev != BLOCKS_PER_BATCH - 1) return;    // not the last block for this batch
    __threadfence();                         // acquire: see all 192 blocks' stores

    // ---------- router for batch b (finisher block only) ----------
    __shared__ float fused[FAN];
    __shared__ float logits_s[E_];
    __shared__ int   sel_s[K_];

    for (int i = tid; i < C_; i += 256) fused[i] = pooled[b * C_ + i];

    // softmax(task_cls[b]) -> fused[768..867]; wave 0 handles all 100 elems
    if (tid < 64) {
        float v1 = task_cls[b * NCLS + tid];
        bool has2 = (tid + 64) < NCLS;
        float v2 = has2 ? task_cls[b * NCLS + tid + 64] : -INFINITY;
        float m = fmaxf(v1, v2);
        #pragma unroll
        for (int off = 32; off > 0; off >>= 1) m = fmaxf(m, __shfl_down(m, off));
        m = __shfl(m, 0);
        float e1 = __expf(v1 - m);
        float e2 = has2 ? __expf(v2 - m) : 0.0f;
        float sm = e1 + e2;
        #pragma unroll
        for (int off = 32; off > 0; off >>= 1) sm += __shfl_down(sm, off);
        sm = __shfl(sm, 0);
        float inv = 1.0f / sm;
        fused[C_ + tid] = e1 * inv;
        if (has2) fused[C_ + tid + 64] = e2 * inv;
    }
    __syncthreads();

    // 16 expert dot products: wave w handles experts 4w..4w+3
    #pragma unroll
    for (int q = 0; q < 4; ++q) {
        const int e = wav * 4 + q;
        const float* wr = Wm + (size_t)e * FAN;
        float acc = 0.0f;
        for (int j = lane; j < FAN; j += 64) acc += fused[j] * wr[j];
        #pragma unroll
        for (int off = 32; off > 0; off >>= 1) acc += __shfl_down(acc, off);
        if (lane == 0) {
            float lg = acc + bias[e];
            logits_s[e] = lg;
            out[b * E_ + e] = lg;                 // router_logits [B,E] @ 0
        }
    }
    __syncthreads();

    // top-2 (strict > keeps lowest index on ties, matching lax.top_k)
    if (tid == 0) {
        float m1 = -INFINITY, m2 = -INFINITY;
        int i1 = 0, i2 = 0;
        #pragma unroll
        for (int e = 0; e < E_; ++e) {
            float v = logits_s[e];
            if (v > m1) { m2 = m1; i2 = i1; m1 = v; i1 = e; }
            else if (v > m2) { m2 = v; i2 = e; }
        }
        float r = expf(m2 - m1);
        float w0 = 1.0f / (1.0f + r);
        float w1 = r * w0;
        out[1024 + b * K_ + 0] = w0;              // router_weights [B,K] @ 1024
        out[1024 + b * K_ + 1] = w1;
        out[1152 + b * K_ + 0] = (float)i1;       // selected_experts [B,K] @ 1152
        out[1152 + b * K_ + 1] = (float)i2;
        sel_s[0] = i1; sel_s[1] = i2;
    }
    __syncthreads();

    // expert_mask [E,K,B] @ 1280 : flat e*K*B + k*B + b
    if (tid < E_ * K_) {
        int e = tid >> 1;
        int k = tid & 1;
        out[1280 + e * (K_ * B_) + k * B_ + b] = (sel_s[k] == e) ? 1.0f : 0.0f;
    }
}

extern "C" void kernel_launch(void* const* d_in, const int* in_sizes, int n_in,
                              void* d_out, int out_size, void* d_ws, size_t ws_size,
                              hipStream_t stream) {
    const float* hidden   = (const float*)d_in[0];  // [64,768,32,32]
    const float* task_cls = (const float*)d_in[1];  // [64,100]
    const float* Wm       = (const float*)d_in[2];  // [16,868]
    const float* bias     = (const float*)d_in[3];  // [16]
    float* out = (float*)d_out;

    unsigned int* counters = (unsigned int*)d_ws;           // 64 uints
    float* pooled = (float*)((char*)d_ws + 1024);           // B*C floats

    (void)hipMemsetAsync(counters, 0, B_ * sizeof(unsigned int), stream);
    fused_router<<<NBLK, 256, 0, stream>>>(hidden, task_cls, Wm, bias, out, pooled, counters);
}

// Round 5
// 53.672 us; speedup vs baseline: 30.1308x; 30.1308x over previous
//
#include <hip/hip_runtime.h>
#include <math.h>

#define B_   64
#define C_   768
#define HW_  1024          // 32*32
#define NCLS 100
#define E_   16
#define K_   2
#define FAN  (C_ + NCLS)   // 868

typedef float vfloat4 __attribute__((ext_vector_type(4)));

// ---------------- Kernel 1: adaptive avg pool ----------------
// 49152 (b,c) rows of 1024 floats. One wave per TWO rows:
// 8 independent float4 loads per thread in flight before any reduction.
// 24576 waves -> 6144 blocks of 256 threads.
__global__ __launch_bounds__(256) void pool_kernel(const float* __restrict__ x,
                                                   float* __restrict__ pooled) {
    const int wave = (blockIdx.x * 256 + threadIdx.x) >> 6;   // 0..24575
    const int lane = threadIdx.x & 63;
    const int r0   = wave * 2;                                // first of 2 rows

    const vfloat4* p0 = reinterpret_cast<const vfloat4*>(x + (size_t)r0 * HW_);
    const vfloat4* p1 = reinterpret_cast<const vfloat4*>(x + (size_t)(r0 + 1) * HW_);
    vfloat4 a0 = p0[lane];
    vfloat4 a1 = p0[lane + 64];
    vfloat4 a2 = p0[lane + 128];
    vfloat4 a3 = p0[lane + 192];
    vfloat4 b0 = p1[lane];
    vfloat4 b1 = p1[lane + 64];
    vfloat4 b2 = p1[lane + 128];
    vfloat4 b3 = p1[lane + 192];

    float s0 = (a0.x + a0.y + a0.z + a0.w) + (a1.x + a1.y + a1.z + a1.w)
             + (a2.x + a2.y + a2.z + a2.w) + (a3.x + a3.y + a3.z + a3.w);
    float s1 = (b0.x + b0.y + b0.z + b0.w) + (b1.x + b1.y + b1.z + b1.w)
             + (b2.x + b2.y + b2.z + b2.w) + (b3.x + b3.y + b3.z + b3.w);

    #pragma unroll
    for (int off = 32; off > 0; off >>= 1) {
        s0 += __shfl_down(s0, off);
        s1 += __shfl_down(s1, off);
    }
    if (lane == 0) {
        pooled[r0]     = s0 * (1.0f / 1024.0f);
        pooled[r0 + 1] = s1 * (1.0f / 1024.0f);
    }
}

// ---------------- Kernel 2: softmax + gate + top-2 + outputs ----------------
// One block per batch element. 256 threads = 4 waves.
__global__ __launch_bounds__(256) void router_kernel(const float* __restrict__ pooled,
                                                     const float* __restrict__ task_cls,
                                                     const float* __restrict__ Wm,
                                                     const float* __restrict__ bias,
                                                     float* __restrict__ out) {
    const int b    = blockIdx.x;
    const int tid  = threadIdx.x;
    const int lane = tid & 63;
    const int wav  = tid >> 6;

    __shared__ float fused[FAN];
    __shared__ float logits_s[E_];
    __shared__ int   sel_s[K_];

    for (int i = tid; i < C_; i += 256) fused[i] = pooled[b * C_ + i];

    // softmax(task_cls[b]) -> fused[768..867]; wave 0 handles all 100 elems
    if (tid < 64) {
        float v1 = task_cls[b * NCLS + tid];
        bool has2 = (tid + 64) < NCLS;
        float v2 = has2 ? task_cls[b * NCLS + tid + 64] : -INFINITY;
        float m = fmaxf(v1, v2);
        #pragma unroll
        for (int off = 32; off > 0; off >>= 1) m = fmaxf(m, __shfl_down(m, off));
        m = __shfl(m, 0);
        float e1 = __expf(v1 - m);
        float e2 = has2 ? __expf(v2 - m) : 0.0f;
        float sm = e1 + e2;
        #pragma unroll
        for (int off = 32; off > 0; off >>= 1) sm += __shfl_down(sm, off);
        sm = __shfl(sm, 0);
        float inv = 1.0f / sm;
        fused[C_ + tid] = e1 * inv;
        if (has2) fused[C_ + tid + 64] = e2 * inv;
    }
    __syncthreads();

    // 16 expert dot products: wave w handles experts 4w..4w+3
    #pragma unroll
    for (int q = 0; q < 4; ++q) {
        const int e = wav * 4 + q;
        const float* wr = Wm + (size_t)e * FAN;
        float acc = 0.0f;
        for (int j = lane; j < FAN; j += 64) acc += fused[j] * wr[j];
        #pragma unroll
        for (int off = 32; off > 0; off >>= 1) acc += __shfl_down(acc, off);
        if (lane == 0) {
            float lg = acc + bias[e];
            logits_s[e] = lg;
            out[b * E_ + e] = lg;                 // router_logits [B,E] @ 0
        }
    }
    __syncthreads();

    // top-2 (strict > keeps lowest index on ties, matching lax.top_k)
    if (tid == 0) {
        float m1 = -INFINITY, m2 = -INFINITY;
        int i1 = 0, i2 = 0;
        #pragma unroll
        for (int e = 0; e < E_; ++e) {
            float v = logits_s[e];
            if (v > m1) { m2 = m1; i2 = i1; m1 = v; i1 = e; }
            else if (v > m2) { m2 = v; i2 = e; }
        }
        float r = expf(m2 - m1);
        float w0 = 1.0f / (1.0f + r);
        float w1 = r * w0;
        out[1024 + b * K_ + 0] = w0;              // router_weights [B,K] @ 1024
        out[1024 + b * K_ + 1] = w1;
        out[1152 + b * K_ + 0] = (float)i1;       // selected_experts [B,K] @ 1152
        out[1152 + b * K_ + 1] = (float)i2;
        sel_s[0] = i1; sel_s[1] = i2;
    }
    __syncthreads();

    // expert_mask [E,K,B] @ 1280 : flat e*K*B + k*B + b
    if (tid < E_ * K_) {
        int e = tid >> 1;
        int k = tid & 1;
        out[1280 + e * (K_ * B_) + k * B_ + b] = (sel_s[k] == e) ? 1.0f : 0.0f;
    }
}

extern "C" void kernel_launch(void* const* d_in, const int* in_sizes, int n_in,
                              void* d_out, int out_size, void* d_ws, size_t ws_size,
                              hipStream_t stream) {
    const float* hidden   = (const float*)d_in[0];  // [64,768,32,32]
    const float* task_cls = (const float*)d_in[1];  // [64,100]
    const float* Wm       = (const float*)d_in[2];  // [16,868]
    const float* bias     = (const float*)d_in[3];  // [16]
    float* out = (float*)d_out;
    float* pooled = (float*)d_ws;                   // B*C floats = 192 KiB

    // 49152 rows, 2 rows per wave, 4 waves per block -> 6144 blocks
    pool_kernel<<<6144, 256, 0, stream>>>(hidden, pooled);
    router_kernel<<<B_, 256, 0, stream>>>(pooled, task_cls, Wm, bias, out);
}